// Round 5
// baseline (192.115 us; speedup 1.0000x reference)
//
#include <hip/hip_runtime.h>

// Problem constants: B=4, T=1024, F=500, H=128, P=64
// All external buffers fp32. Internal GEMMs bf16 (fp32 MFMA accum).
// out = [probs (B*T*P=262144), all_states (T*B*H=524288)] fp32
//
// GEMM structure: no LDS in main loops. B-fragments in registers, A-fragments
// loaded directly from global (operands are L1/L2-resident: S=1MB, Wc=2MB,
// W_ihp=384KB). 16x16x32 bf16 MFMA, wave-tile 16m x 32n.
//
// ws layout:
//   x_pad   [0,         4194304)  4096x512 bf16 (K padded 500->512, zero tail)
//   W_ihp   [4194304,   4587520)  384x512  bf16
//   gi_bf   [4587520,   7733248)  4096x384 bf16
//   S_bf    [7733248,   8781824)  4096x128 bf16 ([T,B,H] rows sr=t*4+b)
//   Wc      [8781824,  10878976)  64x128x128 bf16 (folded ctx weights)
//   partial [10878976, 15073280)  2 x 4096x128 fp32 (ctx split-K partials)

typedef short bf16x8 __attribute__((ext_vector_type(8)));
typedef float f32x4 __attribute__((ext_vector_type(4)));
typedef unsigned short u16;
typedef unsigned int u32;

__device__ __forceinline__ float bf2f(u16 u) {
  union { u32 i; float f; } v; v.i = ((u32)u) << 16; return v.f;
}
__device__ __forceinline__ u16 f2bf(float f) {
  union { float f; u32 i; } v; v.f = f;
  u32 u = v.i;
  return (u16)((u + 0x7FFFu + ((u >> 16) & 1u)) >> 16);
}
__device__ __forceinline__ u32 pack2(float a, float b) {
  return (u32)f2bf(a) | ((u32)f2bf(b) << 16);
}
__device__ __forceinline__ float sigmoidf_(float x) {
  return 1.0f / (1.0f + __expf(-x));
}

// blocks [0,128): Wc[p][h'][h] = W_ctx[h', 8192 + h*64 + p] (+ part1 row sums
//   folded into p==0), via coalesced loads + LDS transpose.
// blocks [128,1248): bf16-convert & pad x (1024 blocks) and W_ih (96 blocks).
__global__ __launch_bounds__(256) void k_prep(const float* __restrict__ W_ctx,
                                              const float* __restrict__ x,
                                              const float* __restrict__ W_ih,
                                              u16* __restrict__ Wc,
                                              u16* __restrict__ x_pad,
                                              u16* __restrict__ W_ihp) {
  const int tid = threadIdx.x;
  if (blockIdx.x < 128) {
    __shared__ float t1[128][68];   // part1 [h][q], +4 pad
    __shared__ float t2[128][68];   // part2 [h][p]
    __shared__ float s1[128];
    const int hp = blockIdx.x;
    const float* wrow = W_ctx + hp * 16384;
    for (int it = 0; it < 8; ++it) {
      int i = it * 256 + tid;
      int j = i * 4;
      int h = j >> 6, q = j & 63;
      *(float4*)&t1[h][q] = *(const float4*)(wrow + j);
      *(float4*)&t2[h][q] = *(const float4*)(wrow + 8192 + j);
    }
    __syncthreads();
    if (tid < 128) {
      float s = 0.f;
      for (int q = 0; q < 64; ++q) s += t1[tid][q];
      s1[tid] = s;
    }
    __syncthreads();
    for (int it = 0; it < 8; ++it) {
      int i = it * 256 + tid;
      int p = i >> 5, h0 = (i & 31) * 4;
      float v0 = t2[h0 + 0][p], v1 = t2[h0 + 1][p];
      float v2 = t2[h0 + 2][p], v3 = t2[h0 + 3][p];
      if (p == 0) { v0 += s1[h0]; v1 += s1[h0 + 1]; v2 += s1[h0 + 2]; v3 += s1[h0 + 3]; }
      uint2 o; o.x = pack2(v0, v1); o.y = pack2(v2, v3);
      *(uint2*)(Wc + p * 16384 + hp * 128 + h0) = o;
    }
  } else {
    int idx = (blockIdx.x - 128) * 256 + tid;   // 286720 = 262144 + 24576
    const float* src; u16* dst; int row, c8;
    if (idx < 262144) { row = idx >> 6; c8 = (idx & 63) * 8; src = x;   dst = x_pad; }
    else { idx -= 262144; row = idx >> 6; c8 = (idx & 63) * 8; src = W_ih; dst = W_ihp; }
    float4 a = make_float4(0.f, 0.f, 0.f, 0.f), b = a;
    if (c8 < 500)     a = *(const float4*)(src + (size_t)row * 500 + c8);
    if (c8 + 4 < 500) b = *(const float4*)(src + (size_t)row * 500 + c8 + 4);
    uint4 o; o.x = pack2(a.x, a.y); o.y = pack2(a.z, a.w);
    o.z = pack2(b.x, b.y); o.w = pack2(b.z, b.w);
    *(uint4*)(dst + (size_t)row * 512 + c8) = o;
  }
}

// gi = x_pad @ W_ihp^T  (M=4096, N=384, K=512). Grid 768 x 256 threads.
// Wave-tile 16m x 32n; B-frags in regs per K-chunk, A straight from global.
__global__ __launch_bounds__(256) void k_gemm_gi(const u16* __restrict__ A,
                                                 const u16* __restrict__ Bw,
                                                 u16* __restrict__ gi_bf) {
  const int tid = threadIdx.x;
  const int w = tid >> 6, lane = tid & 63;
  const int l15 = lane & 15, quad = lane >> 4;
  const int nt = blockIdx.x >> 6;               // 0..11 (same for all 4 waves)
  const int mt = (blockIdx.x & 63) * 4 + w;     // 0..255
  f32x4 acc0 = (f32x4){0.f, 0.f, 0.f, 0.f};
  f32x4 acc1 = (f32x4){0.f, 0.f, 0.f, 0.f};
  const u16* aptr  = A  + (size_t)(mt * 16 + l15) * 512 + quad * 8;
  const u16* bptr0 = Bw + (size_t)(nt * 32 + l15) * 512 + quad * 8;
  const u16* bptr1 = bptr0 + 16 * 512;
#pragma unroll
  for (int kb = 0; kb < 4; ++kb) {
    bf16x8 Af[4], B0[4], B1[4];
#pragma unroll
    for (int s = 0; s < 4; ++s) {
      int k = kb * 128 + s * 32;
      Af[s] = *(const bf16x8*)(aptr + k);
      B0[s] = *(const bf16x8*)(bptr0 + k);
      B1[s] = *(const bf16x8*)(bptr1 + k);
    }
#pragma unroll
    for (int s = 0; s < 4; ++s) {
      acc0 = __builtin_amdgcn_mfma_f32_16x16x32_bf16(Af[s], B0[s], acc0, 0, 0, 0);
      acc1 = __builtin_amdgcn_mfma_f32_16x16x32_bf16(Af[s], B1[s], acc1, 0, 0, 0);
    }
  }
#pragma unroll
  for (int rg = 0; rg < 4; ++rg) {
    int m = mt * 16 + quad * 4 + rg;            // C/D: row=(lane>>4)*4+reg
    gi_bf[m * 384 + nt * 32 + l15]      = f2bf(acc0[rg]);
    gi_bf[m * 384 + nt * 32 + 16 + l15] = f2bf(acc1[rg]);
  }
}

// GRU gates with h=0: s = (1-sig(gz+bz)) * tanh(gn + sig(gr+br)*bn_hh).
__global__ void k_states(const u16* __restrict__ gi_bf,
                         const float* __restrict__ b_ih, const float* __restrict__ b_hh,
                         u16* __restrict__ S_bf, float* __restrict__ out_states) {
  int g = blockIdx.x * 256 + threadIdx.x;  // 4096*128
  int r = g >> 7, h = g & 127;
  float xr = bf2f(gi_bf[r * 384 + h])       + b_ih[h]       + b_hh[h];
  float xz = bf2f(gi_bf[r * 384 + 128 + h]) + b_ih[128 + h] + b_hh[128 + h];
  float xn = bf2f(gi_bf[r * 384 + 256 + h]) + b_ih[256 + h];
  float rg = sigmoidf_(xr);
  float zg = sigmoidf_(xz);
  float n = tanhf(xn + rg * b_hh[256 + h]);
  float s = (1.f - zg) * n;
  int b = r >> 10, t = r & 1023;
  S_bf[(t * 4 + b) * 128 + h] = f2bf(s);
  out_states[(t * 4 + b) * 128 + h] = s;
}

// Context GEMM: gate_pre[t,b,:] = sum_p Wc_p @ s[max(t-p,0),b].
// Grid (64 m-groups, 4 n-tiles, 2 K-halves). Wave-tile 16m x 32n; per p the
// A rows are S_bf rows shifted by 4p (per-lane clamp in the address).
// B-frags (Wc p-slice) in regs, software-pipelined one p ahead. No LDS.
__global__ __launch_bounds__(256) void k_gemm_ctx(const u16* __restrict__ S_bf,
                                                  const u16* __restrict__ Wc,
                                                  float* __restrict__ partial) {
  const int tid = threadIdx.x;
  const int w = tid >> 6, lane = tid & 63;
  const int l15 = lane & 15, quad = lane >> 4;
  const int mt = blockIdx.x * 4 + w;       // 0..255
  const int nt = blockIdx.y;               // 0..3
  const int kc = blockIdx.z;               // 0..1 -> p in [kc*32, kc*32+32)
  const int sr = mt * 16 + l15;
  const int t = sr >> 2, b = sr & 3;
  f32x4 acc0 = (f32x4){0.f, 0.f, 0.f, 0.f};
  f32x4 acc1 = (f32x4){0.f, 0.f, 0.f, 0.f};
  const u16* bbase = Wc + (size_t)(nt * 32 + l15) * 128 + quad * 8;

  bf16x8 Af[4], B0[4], B1[4];
  {
    int p = kc * 32;
    int srp = (t - p < 0) ? b : (sr - 4 * p);
    const u16* ap = S_bf + (size_t)srp * 128 + quad * 8;
    const u16* bp = bbase + (size_t)p * 16384;
#pragma unroll
    for (int s = 0; s < 4; ++s) {
      Af[s] = *(const bf16x8*)(ap + s * 32);
      B0[s] = *(const bf16x8*)(bp + s * 32);
      B1[s] = *(const bf16x8*)(bp + 16 * 128 + s * 32);
    }
  }
#pragma unroll 2
  for (int pi = 0; pi < 32; ++pi) {
    bf16x8 nA[4], nB0[4], nB1[4];
    if (pi < 31) {
      int p = kc * 32 + pi + 1;
      int srp = (t - p < 0) ? b : (sr - 4 * p);
      const u16* ap = S_bf + (size_t)srp * 128 + quad * 8;
      const u16* bp = bbase + (size_t)p * 16384;
#pragma unroll
      for (int s = 0; s < 4; ++s) {
        nA[s] = *(const bf16x8*)(ap + s * 32);
        nB0[s] = *(const bf16x8*)(bp + s * 32);
        nB1[s] = *(const bf16x8*)(bp + 16 * 128 + s * 32);
      }
    }
#pragma unroll
    for (int s = 0; s < 4; ++s) {
      acc0 = __builtin_amdgcn_mfma_f32_16x16x32_bf16(Af[s], B0[s], acc0, 0, 0, 0);
      acc1 = __builtin_amdgcn_mfma_f32_16x16x32_bf16(Af[s], B1[s], acc1, 0, 0, 0);
    }
#pragma unroll
    for (int s = 0; s < 4; ++s) { Af[s] = nA[s]; B0[s] = nB0[s]; B1[s] = nB1[s]; }
  }
  float* op = partial + (size_t)kc * 524288;
#pragma unroll
  for (int rg = 0; rg < 4; ++rg) {
    int m = mt * 16 + quad * 4 + rg;
    op[m * 128 + nt * 32 + l15]      = acc0[rg];
    op[m * 128 + nt * 32 + 16 + l15] = acc1[rg];
  }
}

// Reduce 2 partials + b_ctx -> sigmoid gate; gated = states(fp32)*gate; FC+sig+clip.
__global__ __launch_bounds__(256) void k_epilogue(const float* __restrict__ partial,
                                                  const float* __restrict__ states,
                                                  const float* __restrict__ b_ctx,
                                                  const float* __restrict__ W_fc,
                                                  const float* __restrict__ b_fc,
                                                  float* __restrict__ out_probs) {
  __shared__ float WfcT[128][68];   // [h][p'] transposed, conflict-free dot
  __shared__ float gated[8][128];
  const int tid = threadIdx.x;
  const int row0 = blockIdx.x * 8;
  for (int it = 0; it < 32; ++it) {
    int i = it * 256 + tid;
    int pp = i >> 7, h = i & 127;
    WfcT[h][pp] = W_fc[i];
  }
  for (int it = 0; it < 4; ++it) {
    int i = it * 256 + tid;
    int lr = i >> 7, h = i & 127;
    int sr = row0 + lr;
    float gp = b_ctx[h] + partial[sr * 128 + h] + partial[524288 + sr * 128 + h];
    gated[lr][h] = states[sr * 128 + h] * sigmoidf_(gp);
  }
  __syncthreads();
  for (int it = 0; it < 2; ++it) {
    int o = it * 256 + tid;
    int lr = o >> 6, pp = o & 63;
    int sr = row0 + lr;
    float dot = 0.f;
#pragma unroll
    for (int h = 0; h < 128; ++h) dot += gated[lr][h] * WfcT[h][pp];
    float pv = sigmoidf_(dot + b_fc[pp]);
    pv = (pv > 0.001f) ? pv : 0.001f;
    pv = (pv < 0.999f) ? pv : 0.999f;
    int t = sr >> 2, b = sr & 3;
    out_probs[(b * 1024 + t) * 64 + pp] = pv;
  }
}

extern "C" void kernel_launch(void* const* d_in, const int* in_sizes, int n_in,
                              void* d_out, int out_size, void* d_ws, size_t ws_size,
                              hipStream_t stream) {
  const float* x     = (const float*)d_in[0];
  const float* W_ih  = (const float*)d_in[1];
  // d_in[2] = W_hh: unused (hidden state is always 0 in the reference)
  const float* b_ih  = (const float*)d_in[3];
  const float* b_hh  = (const float*)d_in[4];
  const float* W_ctx = (const float*)d_in[5];
  const float* b_ctx = (const float*)d_in[6];
  const float* W_fc  = (const float*)d_in[7];
  const float* b_fc  = (const float*)d_in[8];
  float* out = (float*)d_out;

  char* ws = (char*)d_ws;
  u16*   x_pad   = (u16*)  (ws + 0);           // 4,194,304 B
  u16*   W_ihp   = (u16*)  (ws + 4194304);     //   393,216 B
  u16*   gi_bf   = (u16*)  (ws + 4587520);     // 3,145,728 B
  u16*   S_bf    = (u16*)  (ws + 7733248);     // 1,048,576 B
  u16*   Wc      = (u16*)  (ws + 8781824);     // 2,097,152 B
  float* partial = (float*)(ws + 10878976);    // 4,194,304 B
  // total ws used: 15,073,280 bytes

  k_prep<<<1248, 256, 0, stream>>>(W_ctx, x, W_ih, Wc, x_pad, W_ihp);
  k_gemm_gi<<<768, 256, 0, stream>>>(x_pad, W_ihp, gi_bf);
  k_states<<<2048, 256, 0, stream>>>(gi_bf, b_ih, b_hh, S_bf, out + 262144);
  k_gemm_ctx<<<dim3(64, 4, 2), 256, 0, stream>>>(S_bf, Wc, partial);
  k_epilogue<<<512, 256, 0, stream>>>(partial, out + 262144, b_ctx, W_fc, b_fc, out);
}

// Round 6
// 170.289 us; speedup vs baseline: 1.1282x; 1.1282x over previous
//
#include <hip/hip_runtime.h>

// Problem constants: B=4, T=1024, F=500, H=128, P=64
// All external buffers fp32. Internal GEMMs bf16 (fp32 MFMA accum).
// out = [probs (B*T*P=262144), all_states (T*B*H=524288)] fp32
//
// GEMM structure (m97-style): 64m x 128n block tile, 2 waves (wave-tile
// 64x64), BK=32, double-buffered LDS staged via VGPRs, one barrier/step.
//
// ws layout:
//   x_pad   [0,         4194304)  4096x512 bf16 (K padded 500->512, zero tail)
//   W_ihp   [4194304,   4587520)  384x512  bf16
//   gi_bf   [4587520,   7733248)  4096x384 bf16
//   S_bf    [7733248,   8781824)  4096x128 bf16 ([T,B,H] rows sr=t*4+b)
//   Wc      [8781824,  10878976)  64x128x128 bf16 (folded ctx weights)
//   partial [10878976, 27656192)  8 x 4096x128 fp32 (ctx split-K partials)

typedef short bf16x8 __attribute__((ext_vector_type(8)));
typedef float f32x4 __attribute__((ext_vector_type(4)));
typedef unsigned short u16;
typedef unsigned int u32;

__device__ __forceinline__ float bf2f(u16 u) {
  union { u32 i; float f; } v; v.i = ((u32)u) << 16; return v.f;
}
__device__ __forceinline__ u16 f2bf(float f) {
  union { float f; u32 i; } v; v.f = f;
  u32 u = v.i;
  return (u16)((u + 0x7FFFu + ((u >> 16) & 1u)) >> 16);
}
__device__ __forceinline__ u32 pack2(float a, float b) {
  return (u32)f2bf(a) | ((u32)f2bf(b) << 16);
}
__device__ __forceinline__ float sigmoidf_(float x) {
  return 1.0f / (1.0f + __expf(-x));
}

// blocks [0,128): Wc[p][h'][h] = W_ctx[h', 8192 + h*64 + p] (+ part1 row sums
//   folded into p==0), via coalesced loads + LDS transpose.
// blocks [128,1248): bf16-convert & pad x (1024 blocks) and W_ih (96 blocks).
__global__ __launch_bounds__(256) void k_prep(const float* __restrict__ W_ctx,
                                              const float* __restrict__ x,
                                              const float* __restrict__ W_ih,
                                              u16* __restrict__ Wc,
                                              u16* __restrict__ x_pad,
                                              u16* __restrict__ W_ihp) {
  const int tid = threadIdx.x;
  if (blockIdx.x < 128) {
    __shared__ float t1[128][68];   // part1 [h][q], +4 pad
    __shared__ float t2[128][68];   // part2 [h][p]
    __shared__ float s1[128];
    const int hp = blockIdx.x;
    const float* wrow = W_ctx + hp * 16384;
    for (int it = 0; it < 8; ++it) {
      int i = it * 256 + tid;
      int j = i * 4;
      int h = j >> 6, q = j & 63;
      *(float4*)&t1[h][q] = *(const float4*)(wrow + j);
      *(float4*)&t2[h][q] = *(const float4*)(wrow + 8192 + j);
    }
    __syncthreads();
    if (tid < 128) {
      float s = 0.f;
      for (int q = 0; q < 64; ++q) s += t1[tid][q];
      s1[tid] = s;
    }
    __syncthreads();
    for (int it = 0; it < 8; ++it) {
      int i = it * 256 + tid;
      int p = i >> 5, h0 = (i & 31) * 4;
      float v0 = t2[h0 + 0][p], v1 = t2[h0 + 1][p];
      float v2 = t2[h0 + 2][p], v3 = t2[h0 + 3][p];
      if (p == 0) { v0 += s1[h0]; v1 += s1[h0 + 1]; v2 += s1[h0 + 2]; v3 += s1[h0 + 3]; }
      uint2 o; o.x = pack2(v0, v1); o.y = pack2(v2, v3);
      *(uint2*)(Wc + p * 16384 + hp * 128 + h0) = o;
    }
  } else {
    int idx = (blockIdx.x - 128) * 256 + tid;   // 286720 = 262144 + 24576
    const float* src; u16* dst; int row, c8;
    if (idx < 262144) { row = idx >> 6; c8 = (idx & 63) * 8; src = x;   dst = x_pad; }
    else { idx -= 262144; row = idx >> 6; c8 = (idx & 63) * 8; src = W_ih; dst = W_ihp; }
    float4 a = make_float4(0.f, 0.f, 0.f, 0.f), b = a;
    if (c8 < 500)     a = *(const float4*)(src + (size_t)row * 500 + c8);
    if (c8 + 4 < 500) b = *(const float4*)(src + (size_t)row * 500 + c8 + 4);
    uint4 o; o.x = pack2(a.x, a.y); o.y = pack2(a.z, a.w);
    o.z = pack2(b.x, b.y); o.w = pack2(b.z, b.w);
    *(uint4*)(dst + (size_t)row * 512 + c8) = o;
  }
}

// gi = x_pad @ W_ihp^T  (M=4096, N=384, K=512). Grid (64 m-tiles, 3 n-tiles),
// 128 threads. Block tile 64x128, wave-tile 64x64, BK=32, dbuf LDS.
__global__ __launch_bounds__(128, 2) void k_gemm_gi(const u16* __restrict__ A,
                                                    const u16* __restrict__ Bw,
                                                    u16* __restrict__ gi_bf) {
  __shared__ u16 Asm[2][64][40];    // stride 40 u16 = 80 B (16B-aligned rows)
  __shared__ u16 Bsm[2][128][40];
  const int tid = threadIdx.x;
  const int w = tid >> 6, lane = tid & 63;
  const int l15 = lane & 15, quad = lane >> 4;
  const int m0 = blockIdx.x * 64;
  const int n0 = blockIdx.y * 128;
  f32x4 acc[4][4];
  for (int i = 0; i < 4; ++i)
    for (int j = 0; j < 4; ++j) acc[i][j] = (f32x4){0.f, 0.f, 0.f, 0.f};

  uint4 ra[2], rb[4];
  auto load_step = [&](int s) {
    int kc = s * 32;
#pragma unroll
    for (int j = 0; j < 2; ++j) {
      int c = j * 128 + tid;
      ra[j] = *(const uint4*)(A + (size_t)(m0 + (c >> 2)) * 512 + kc + (c & 3) * 8);
    }
#pragma unroll
    for (int j = 0; j < 4; ++j) {
      int c = j * 128 + tid;
      rb[j] = *(const uint4*)(Bw + (size_t)(n0 + (c >> 2)) * 512 + kc + (c & 3) * 8);
    }
  };
  auto write_step = [&](int b) {
#pragma unroll
    for (int j = 0; j < 2; ++j) {
      int c = j * 128 + tid;
      *(uint4*)&Asm[b][c >> 2][(c & 3) * 8] = ra[j];
    }
#pragma unroll
    for (int j = 0; j < 4; ++j) {
      int c = j * 128 + tid;
      *(uint4*)&Bsm[b][c >> 2][(c & 3) * 8] = rb[j];
    }
  };

  load_step(0); write_step(0); __syncthreads();
  for (int s = 0; s < 16; ++s) {
    int cur = s & 1;
    if (s < 15) load_step(s + 1);
    bf16x8 af[4], bfr[4];
#pragma unroll
    for (int mt = 0; mt < 4; ++mt) af[mt] = *(const bf16x8*)&Asm[cur][mt * 16 + l15][quad * 8];
#pragma unroll
    for (int nt = 0; nt < 4; ++nt) bfr[nt] = *(const bf16x8*)&Bsm[cur][w * 64 + nt * 16 + l15][quad * 8];
#pragma unroll
    for (int mt = 0; mt < 4; ++mt)
#pragma unroll
      for (int nt = 0; nt < 4; ++nt)
        acc[mt][nt] = __builtin_amdgcn_mfma_f32_16x16x32_bf16(af[mt], bfr[nt], acc[mt][nt], 0, 0, 0);
    if (s < 15) write_step((s + 1) & 1);
    __syncthreads();
  }
  for (int mt = 0; mt < 4; ++mt)
    for (int nt = 0; nt < 4; ++nt)
      for (int rg = 0; rg < 4; ++rg) {
        int m = m0 + mt * 16 + quad * 4 + rg;    // C/D: row=(lane>>4)*4+reg
        int n = n0 + w * 64 + nt * 16 + l15;     //      col=lane&15
        gi_bf[m * 384 + n] = f2bf(acc[mt][nt][rg]);
      }
}

// GRU gates with h=0: s = (1-sig(gz+bz)) * tanh(gn + sig(gr+br)*bn_hh).
__global__ void k_states(const u16* __restrict__ gi_bf,
                         const float* __restrict__ b_ih, const float* __restrict__ b_hh,
                         u16* __restrict__ S_bf, float* __restrict__ out_states) {
  int g = blockIdx.x * 256 + threadIdx.x;  // 4096*128
  int r = g >> 7, h = g & 127;
  float xr = bf2f(gi_bf[r * 384 + h])       + b_ih[h]       + b_hh[h];
  float xz = bf2f(gi_bf[r * 384 + 128 + h]) + b_ih[128 + h] + b_hh[128 + h];
  float xn = bf2f(gi_bf[r * 384 + 256 + h]) + b_ih[256 + h];
  float rg = sigmoidf_(xr);
  float zg = sigmoidf_(xz);
  float n = tanhf(xn + rg * b_hh[256 + h]);
  float s = (1.f - zg) * n;
  int b = r >> 10, t = r & 1023;
  S_bf[(t * 4 + b) * 128 + h] = f2bf(s);
  out_states[(t * 4 + b) * 128 + h] = s;
}

// Context GEMM: partial[kc][m][h'] = sum_{p in chunk} Wc_p @ s[max(t-p,0),b].
// Grid (64 m-tiles, 8 K-chunks of 8 p), 128 threads. A rows are S_bf rows
// shifted by 4p (per-lane clamp in the staging address). BK=32 dbuf LDS.
__global__ __launch_bounds__(128, 2) void k_gemm_ctx(const u16* __restrict__ S_bf,
                                                     const u16* __restrict__ Wc,
                                                     float* __restrict__ partial) {
  __shared__ u16 Asm[2][64][40];
  __shared__ u16 Bsm[2][128][40];
  const int tid = threadIdx.x;
  const int w = tid >> 6, lane = tid & 63;
  const int l15 = lane & 15, quad = lane >> 4;
  const int m0 = blockIdx.x * 64;
  const int P0 = blockIdx.y * 8;
  f32x4 acc[4][4];
  for (int i = 0; i < 4; ++i)
    for (int j = 0; j < 4; ++j) acc[i][j] = (f32x4){0.f, 0.f, 0.f, 0.f};

  uint4 ra[2], rb[4];
  auto load_step = [&](int s) {
    int p = P0 + (s >> 2);
    int kc = (s & 3) * 32;
#pragma unroll
    for (int j = 0; j < 2; ++j) {
      int c = j * 128 + tid;
      int m = m0 + (c >> 2);
      int sr2 = ((m >> 2) < p) ? (m & 3) : (m - 4 * p);   // clip(t-p,0) row
      ra[j] = *(const uint4*)(S_bf + (size_t)sr2 * 128 + kc + (c & 3) * 8);
    }
    const u16* wp = Wc + (size_t)p * 16384 + kc;
#pragma unroll
    for (int j = 0; j < 4; ++j) {
      int c = j * 128 + tid;
      rb[j] = *(const uint4*)(wp + (c >> 2) * 128 + (c & 3) * 8);
    }
  };
  auto write_step = [&](int b) {
#pragma unroll
    for (int j = 0; j < 2; ++j) {
      int c = j * 128 + tid;
      *(uint4*)&Asm[b][c >> 2][(c & 3) * 8] = ra[j];
    }
#pragma unroll
    for (int j = 0; j < 4; ++j) {
      int c = j * 128 + tid;
      *(uint4*)&Bsm[b][c >> 2][(c & 3) * 8] = rb[j];
    }
  };

  load_step(0); write_step(0); __syncthreads();
  for (int s = 0; s < 32; ++s) {
    int cur = s & 1;
    if (s < 31) load_step(s + 1);
    bf16x8 af[4], bfr[4];
#pragma unroll
    for (int mt = 0; mt < 4; ++mt) af[mt] = *(const bf16x8*)&Asm[cur][mt * 16 + l15][quad * 8];
#pragma unroll
    for (int nt = 0; nt < 4; ++nt) bfr[nt] = *(const bf16x8*)&Bsm[cur][w * 64 + nt * 16 + l15][quad * 8];
#pragma unroll
    for (int mt = 0; mt < 4; ++mt)
#pragma unroll
      for (int nt = 0; nt < 4; ++nt)
        acc[mt][nt] = __builtin_amdgcn_mfma_f32_16x16x32_bf16(af[mt], bfr[nt], acc[mt][nt], 0, 0, 0);
    if (s < 31) write_step((s + 1) & 1);
    __syncthreads();
  }
  float* op = partial + (size_t)blockIdx.y * 524288;
  for (int mt = 0; mt < 4; ++mt)
    for (int nt = 0; nt < 4; ++nt)
      for (int rg = 0; rg < 4; ++rg) {
        int m = m0 + mt * 16 + quad * 4 + rg;
        int n = w * 64 + nt * 16 + l15;
        op[m * 128 + n] = acc[mt][nt][rg];
      }
}

// Reduce 8 partials + b_ctx -> sigmoid gate; gated = states(fp32)*gate; FC+sig+clip.
__global__ __launch_bounds__(256) void k_epilogue(const float* __restrict__ partial,
                                                  const float* __restrict__ states,
                                                  const float* __restrict__ b_ctx,
                                                  const float* __restrict__ W_fc,
                                                  const float* __restrict__ b_fc,
                                                  float* __restrict__ out_probs) {
  __shared__ float WfcT[128][68];   // [h][p'] transposed, conflict-free dot
  __shared__ float gated[8][128];
  const int tid = threadIdx.x;
  const int row0 = blockIdx.x * 8;
  for (int it = 0; it < 32; ++it) {
    int i = it * 256 + tid;
    int pp = i >> 7, h = i & 127;
    WfcT[h][pp] = W_fc[i];
  }
  for (int it = 0; it < 4; ++it) {
    int i = it * 256 + tid;
    int lr = i >> 7, h = i & 127;
    int sr = row0 + lr;
    float gp = b_ctx[h];
#pragma unroll
    for (int c = 0; c < 8; ++c) gp += partial[(size_t)c * 524288 + sr * 128 + h];
    gated[lr][h] = states[sr * 128 + h] * sigmoidf_(gp);
  }
  __syncthreads();
  for (int it = 0; it < 2; ++it) {
    int o = it * 256 + tid;
    int lr = o >> 6, pp = o & 63;
    int sr = row0 + lr;
    float dot = 0.f;
#pragma unroll
    for (int h = 0; h < 128; ++h) dot += gated[lr][h] * WfcT[h][pp];
    float pv = sigmoidf_(dot + b_fc[pp]);
    pv = (pv > 0.001f) ? pv : 0.001f;
    pv = (pv < 0.999f) ? pv : 0.999f;
    int t = sr >> 2, b = sr & 3;
    out_probs[(b * 1024 + t) * 64 + pp] = pv;
  }
}

extern "C" void kernel_launch(void* const* d_in, const int* in_sizes, int n_in,
                              void* d_out, int out_size, void* d_ws, size_t ws_size,
                              hipStream_t stream) {
  const float* x     = (const float*)d_in[0];
  const float* W_ih  = (const float*)d_in[1];
  // d_in[2] = W_hh: unused (hidden state is always 0 in the reference)
  const float* b_ih  = (const float*)d_in[3];
  const float* b_hh  = (const float*)d_in[4];
  const float* W_ctx = (const float*)d_in[5];
  const float* b_ctx = (const float*)d_in[6];
  const float* W_fc  = (const float*)d_in[7];
  const float* b_fc  = (const float*)d_in[8];
  float* out = (float*)d_out;

  char* ws = (char*)d_ws;
  u16*   x_pad   = (u16*)  (ws + 0);           // 4,194,304 B
  u16*   W_ihp   = (u16*)  (ws + 4194304);     //   393,216 B
  u16*   gi_bf   = (u16*)  (ws + 4587520);     // 3,145,728 B
  u16*   S_bf    = (u16*)  (ws + 7733248);     // 1,048,576 B
  u16*   Wc      = (u16*)  (ws + 8781824);     // 2,097,152 B
  float* partial = (float*)(ws + 10878976);    // 16,777,216 B
  // total ws used: 27,656,192 bytes

  k_prep<<<1248, 256, 0, stream>>>(W_ctx, x, W_ih, Wc, x_pad, W_ihp);
  k_gemm_gi<<<dim3(64, 3), 128, 0, stream>>>(x_pad, W_ihp, gi_bf);
  k_states<<<2048, 256, 0, stream>>>(gi_bf, b_ih, b_hh, S_bf, out + 262144);
  k_gemm_ctx<<<dim3(64, 8), 128, 0, stream>>>(S_bf, Wc, partial);
  k_epilogue<<<512, 256, 0, stream>>>(partial, out + 262144, b_ctx, W_fc, b_fc, out);
}